// Round 6
// baseline (624.865 us; speedup 1.0000x reference)
//
#include <hip/hip_runtime.h>
#include <math.h>

// Chamfer distance, N=M=16384, D=3, fp32.
// R6: exact pruned NN search (R5 algorithm) with PER-LANE execution.
// R5 post-mortem: 1-wave blocks + block-convergent LDS-tile expansion gave
// 0.96% occupancy and a 435 us straggler tail. Now: one query per lane,
// candidates read directly from the sorted float4 array (512 KB, L2/L1
// resident), no barriers, per-lane window expansion (adjacent sorted
// queries => near-identical windows => low divergence), x4-unrolled
// candidate loop for MLP, 512x64 grid for fine-grained balance.
// Exactness: a lane stops expanding a side only when its best squared
// distance <= squared x-distance to that side's unscanned bucket edge --
// a conservative lower bound on any unscanned point's distance.

constexpr int   NPTS  = 16384;
constexpr int   B     = 512;                  // x-bins
constexpr float X0    = -6.0f;                // bin range [-6, 6] (clamped)
constexpr float XW    = 12.0f / B;
constexpr float INV_W = B / 12.0f;
constexpr int   CB    = 64;                   // bin/scatter blocks (32/set)
constexpr float INF_F = 3.402823466e+38f;

static __device__ __forceinline__ int bucket_of(float x) {
  int b = (int)floorf((x - X0) * INV_W);
  return min(max(b, 0), B - 1);
}

// ---- 1. per-block histograms: cnt_blk[blk][B] (blocks 0..31 = set A) ----
__global__ __launch_bounds__(512) void chamfer_bin(
    const float* __restrict__ p1, const float* __restrict__ p2,
    int* __restrict__ cnt_blk) {
  __shared__ int hist[B];
  const int tid = threadIdx.x;
  hist[tid] = 0;
  __syncthreads();
  const int set = blockIdx.x >> 5;
  const int loc = (blockIdx.x & 31) * 512 + tid;
  const float* __restrict__ pts = set ? p2 : p1;
  atomicAdd(&hist[bucket_of(pts[loc * 3])], 1);
  __syncthreads();
  cnt_blk[blockIdx.x * B + tid] = hist[tid];
}

// ---- 2. scan: bucket starts + per-(block,bin) scatter offsets ----
__global__ __launch_bounds__(B) void chamfer_scan(
    const int* __restrict__ cnt_blk, int* __restrict__ offs_blk,
    int* __restrict__ bstart, float* __restrict__ out) {
  __shared__ int sc[B];
  const int tid = threadIdx.x;
  for (int set = 0; set < 2; ++set) {
    const int kb = set * 32;
    int cnt[32];
    int tot = 0;
#pragma unroll
    for (int k = 0; k < 32; ++k) {
      cnt[k] = cnt_blk[(kb + k) * B + tid];
      tot += cnt[k];
    }
    sc[tid] = tot;
    __syncthreads();
    for (int off = 1; off < B; off <<= 1) {  // Hillis-Steele inclusive
      const int add = (tid >= off) ? sc[tid - off] : 0;
      __syncthreads();
      sc[tid] += add;
      __syncthreads();
    }
    const int base = sc[tid] - tot;  // exclusive
    bstart[set * (B + 1) + tid] = base;
    if (tid == 0) bstart[set * (B + 1) + B] = NPTS;
    int run = base;
#pragma unroll
    for (int k = 0; k < 32; ++k) {
      offs_blk[(kb + k) * B + tid] = run;
      run += cnt[k];
    }
    __syncthreads();  // before sc reuse
  }
  if (tid == 0) out[0] = 0.0f;
}

// ---- 3. scatter to bucket-sorted float4 {x, y, z, ||p||^2} ----
__global__ __launch_bounds__(512) void chamfer_scatter(
    const float* __restrict__ p1, const float* __restrict__ p2,
    const int* __restrict__ offs_blk, float4* __restrict__ scat) {
  __shared__ int hist[B];
  const int tid = threadIdx.x;
  hist[tid] = 0;
  __syncthreads();
  const int set = blockIdx.x >> 5;
  const int loc = (blockIdx.x & 31) * 512 + tid;
  const float* __restrict__ pts = set ? p2 : p1;
  const float x = pts[loc * 3 + 0];
  const float y = pts[loc * 3 + 1];
  const float z = pts[loc * 3 + 2];
  const int b = bucket_of(x);
  const int rank = atomicAdd(&hist[b], 1);  // LDS, low contention
  const int pos = offs_blk[blockIdx.x * B + b] + rank;
  scat[set * NPTS + pos] =
      make_float4(x, y, z, fmaf(x, x, fmaf(y, y, z * z)));
}

// ---- 4. search: one query per lane, per-lane window expansion ----
__global__ __launch_bounds__(64) void chamfer_search(
    const float4* __restrict__ scat, const int* __restrict__ bstart,
    float* __restrict__ out) {
  const int gid = blockIdx.x * 64 + threadIdx.x;  // 0..32767
  const int qset = gid >> 14;
  const int qi = gid & (NPTS - 1);
  const float4 Q = scat[qset * NPTS + qi];
  const float4* __restrict__ ts = scat + (1 - qset) * NPTS;
  const int* __restrict__ tst = bstart + (1 - qset) * (B + 1);

  const float nx = -2.0f * Q.x, ny = -2.0f * Q.y, nz = -2.0f * Q.z;
  float best = INF_F;  // min of (||b||^2 - 2 a.b); true sq-dist = best + Q.w

  auto scan = [&](int s, int e) {
    int i = s;
    for (; i + 4 <= e; i += 4) {
      const float4 c0 = ts[i + 0];
      const float4 c1 = ts[i + 1];
      const float4 c2 = ts[i + 2];
      const float4 c3 = ts[i + 3];
      const float d0 = fmaf(nx, c0.x, fmaf(ny, c0.y, fmaf(nz, c0.z, c0.w)));
      const float d1 = fmaf(nx, c1.x, fmaf(ny, c1.y, fmaf(nz, c1.z, c1.w)));
      const float d2 = fmaf(nx, c2.x, fmaf(ny, c2.y, fmaf(nz, c2.z, c2.w)));
      const float d3 = fmaf(nx, c3.x, fmaf(ny, c3.y, fmaf(nz, c3.z, c3.w)));
      best = fminf(best, fminf(fminf(d0, d1), fminf(d2, d3)));
    }
    for (; i < e; ++i) {
      const float4 c = ts[i];
      best = fminf(best, fmaf(nx, c.x, fmaf(ny, c.y, fmaf(nz, c.z, c.w))));
    }
  };

  const int b0 = bucket_of(Q.x);
  int tl = b0, tr = b0;
  scan(tst[b0], tst[b0 + 1]);

  while (true) {
    const float bsq = best + Q.w;  // best squared distance so far (>= ~0)
    const float dL = Q.x - (X0 + tl * XW);        // to unscanned left edge
    const float dR = (X0 + (tr + 1) * XW) - Q.x;  // to unscanned right edge
    const bool ndL = (tl > 0) && (bsq > dL * dL);
    const bool ndR = (tr < B - 1) && (bsq > dR * dR);
    if (!ndL && !ndR) break;
    if (ndL && (!ndR || dL <= dR)) {
      --tl;
      scan(tst[tl], tst[tl + 1]);
    } else {
      ++tr;
      scan(tst[tr], tst[tr + 1]);
    }
  }

  float d = sqrtf(fmaxf(best + Q.w, 0.0f));
  for (int off = 32; off > 0; off >>= 1) d += __shfl_down(d, off, 64);
  if (threadIdx.x == 0) atomicAdd(out, d);
}

extern "C" void kernel_launch(void* const* d_in, const int* in_sizes, int n_in,
                              void* d_out, int out_size, void* d_ws, size_t ws_size,
                              hipStream_t stream) {
  const float* p1 = (const float*)d_in[0];
  const float* p2 = (const float*)d_in[1];
  float* out = (float*)d_out;

  // ws layout (~772 KB): scat | cnt_blk | offs_blk | bstart
  float4* scat  = (float4*)d_ws;             // 2*NPTS float4 (512 KB)
  int* cnt_blk  = (int*)(scat + 2 * NPTS);   // CB*B (128 KB)
  int* offs_blk = cnt_blk + CB * B;          // CB*B (128 KB)
  int* bstart   = offs_blk + CB * B;         // 2*(B+1)

  chamfer_bin    <<<CB, 512, 0, stream>>>(p1, p2, cnt_blk);
  chamfer_scan   <<<1, B, 0, stream>>>(cnt_blk, offs_blk, bstart, out);
  chamfer_scatter<<<CB, 512, 0, stream>>>(p1, p2, offs_blk, scat);
  chamfer_search <<<512, 64, 0, stream>>>(scat, bstart, out);
}

// Round 7
// 516.775 us; speedup vs baseline: 1.2092x; 1.2092x over previous
//
#include <hip/hip_runtime.h>
#include <math.h>

// Chamfer distance, N=M=16384, D=3, fp32.
// R7: exact pruned NN search executed DENSELY, wave-convergent.
// R5/R6 post-mortem: per-lane (and per-block LDS-tile) sparse execution is
// latency-bound at ~2 waves/CU -- 94% stall, 435-596 us despite 25x less
// math. Fix: one wave per 64 bucket-sorted queries; the wave's candidate
// window in the sorted target array is ONE wave-uniform contiguous range,
// scanned densely: uniform index => ts[j] becomes scalar (SMEM) loads
// broadcast to all lanes; each lane evaluates its own query (3 fma + min,
// the R4-proven dense chain). Bucket-at-a-time expansion with __any votes
// on the exact bucket-edge bound (conservative => exact result).
// Work is rank-balanced: union window ~ 64 ranks + NN-window x density.

constexpr int   NPTS  = 16384;
constexpr int   B     = 512;                  // x-bins
constexpr float X0    = -6.0f;                // bin range [-6, 6] (clamped)
constexpr float XW    = 12.0f / B;
constexpr float INV_W = B / 12.0f;
constexpr int   CB    = 64;                   // bin/scatter blocks (32/set)
constexpr float INF_F = 3.402823466e+38f;

static __device__ __forceinline__ int bucket_of(float x) {
  int b = (int)floorf((x - X0) * INV_W);
  return min(max(b, 0), B - 1);
}

// ---- 1. per-block histograms: cnt_blk[blk][B] (blocks 0..31 = set A) ----
__global__ __launch_bounds__(512) void chamfer_bin(
    const float* __restrict__ p1, const float* __restrict__ p2,
    int* __restrict__ cnt_blk) {
  __shared__ int hist[B];
  const int tid = threadIdx.x;
  hist[tid] = 0;
  __syncthreads();
  const int set = blockIdx.x >> 5;
  const int loc = (blockIdx.x & 31) * 512 + tid;
  const float* __restrict__ pts = set ? p2 : p1;
  atomicAdd(&hist[bucket_of(pts[loc * 3])], 1);
  __syncthreads();
  cnt_blk[blockIdx.x * B + tid] = hist[tid];
}

// ---- 2. scan: bucket starts + per-(block,bin) scatter offsets ----
__global__ __launch_bounds__(B) void chamfer_scan(
    const int* __restrict__ cnt_blk, int* __restrict__ offs_blk,
    int* __restrict__ bstart, float* __restrict__ out) {
  __shared__ int sc[B];
  const int tid = threadIdx.x;
  for (int set = 0; set < 2; ++set) {
    const int kb = set * 32;
    int cnt[32];
    int tot = 0;
#pragma unroll
    for (int k = 0; k < 32; ++k) {
      cnt[k] = cnt_blk[(kb + k) * B + tid];
      tot += cnt[k];
    }
    sc[tid] = tot;
    __syncthreads();
    for (int off = 1; off < B; off <<= 1) {  // Hillis-Steele inclusive
      const int add = (tid >= off) ? sc[tid - off] : 0;
      __syncthreads();
      sc[tid] += add;
      __syncthreads();
    }
    const int base = sc[tid] - tot;  // exclusive
    bstart[set * (B + 1) + tid] = base;
    if (tid == 0) bstart[set * (B + 1) + B] = NPTS;
    int run = base;
#pragma unroll
    for (int k = 0; k < 32; ++k) {
      offs_blk[(kb + k) * B + tid] = run;
      run += cnt[k];
    }
    __syncthreads();  // before sc reuse
  }
  if (tid == 0) out[0] = 0.0f;
}

// ---- 3. scatter to bucket-sorted float4 {x, y, z, ||p||^2} ----
__global__ __launch_bounds__(512) void chamfer_scatter(
    const float* __restrict__ p1, const float* __restrict__ p2,
    const int* __restrict__ offs_blk, float4* __restrict__ scat) {
  __shared__ int hist[B];
  const int tid = threadIdx.x;
  hist[tid] = 0;
  __syncthreads();
  const int set = blockIdx.x >> 5;
  const int loc = (blockIdx.x & 31) * 512 + tid;
  const float* __restrict__ pts = set ? p2 : p1;
  const float x = pts[loc * 3 + 0];
  const float y = pts[loc * 3 + 1];
  const float z = pts[loc * 3 + 2];
  const int b = bucket_of(x);
  const int rank = atomicAdd(&hist[b], 1);  // LDS, low contention
  const int pos = offs_blk[blockIdx.x * B + b] + rank;
  scat[set * NPTS + pos] =
      make_float4(x, y, z, fmaf(x, x, fmaf(y, y, z * z)));
}

// ---- 4. search: one wave per 64 sorted queries, dense uniform window ----
__global__ __launch_bounds__(64) void chamfer_search(
    const float4* __restrict__ scat, const int* __restrict__ bstart,
    float* __restrict__ out) {
  const int wid  = blockIdx.x;          // 0..511
  const int qset = wid >> 8;            // 256 waves per set
  const int lane = threadIdx.x;
  const int qi   = (wid & 255) * 64 + lane;

  const float4 Q = scat[qset * NPTS + qi];
  const float4* __restrict__ ts = scat + (1 - qset) * NPTS;
  const int* __restrict__ tst = bstart + (1 - qset) * (B + 1);

  const float nx = -2.0f * Q.x, ny = -2.0f * Q.y, nz = -2.0f * Q.z;
  float best = INF_F;  // min of (||b||^2 - 2 a.b); true sq-dist = best + Q.w

  // s, e are wave-uniform -> ts[j] is a uniform (scalar-load) access; every
  // lane evaluates the broadcast candidate against its own query.
  auto scan_range = [&](int s, int e) {
    int j = s;
    for (; j + 4 <= e; j += 4) {
      const float4 c0 = ts[j + 0];
      const float4 c1 = ts[j + 1];
      const float4 c2 = ts[j + 2];
      const float4 c3 = ts[j + 3];
      const float d0 = fmaf(nx, c0.x, fmaf(ny, c0.y, fmaf(nz, c0.z, c0.w)));
      const float d1 = fmaf(nx, c1.x, fmaf(ny, c1.y, fmaf(nz, c1.z, c1.w)));
      const float d2 = fmaf(nx, c2.x, fmaf(ny, c2.y, fmaf(nz, c2.z, c2.w)));
      const float d3 = fmaf(nx, c3.x, fmaf(ny, c3.y, fmaf(nz, c3.z, c3.w)));
      best = fminf(best, fminf(fminf(d0, d1), fminf(d2, d3)));
    }
    for (; j < e; ++j) {
      const float4 c = ts[j];
      best = fminf(best, fmaf(nx, c.x, fmaf(ny, c.y, fmaf(nz, c.z, c.w))));
    }
  };

  // initial window: union of the wave's query buckets (sorted => lane 0
  // has the min bucket, lane 63 the max)
  const int b0 = bucket_of(Q.x);
  int tl = __shfl(b0, 0);
  int tr = __shfl(b0, 63);
  scan_range(tst[tl], tst[tr + 1]);

  while (true) {
    const float bsq = fmaxf(best + Q.w, 0.0f);  // best sq-dist so far
    const float dL = Q.x - (X0 + tl * XW);        // to unscanned left edge
    const float dR = (X0 + (tr + 1) * XW) - Q.x;  // to unscanned right edge
    const bool ndL = (tl > 0) && (bsq > dL * dL);
    const bool ndR = (tr < B - 1) && (bsq > dR * dR);
    const bool anyL = __any(ndL);
    const bool anyR = __any(ndR);
    if (!anyL && !anyR) break;
    if (anyL) { --tl; scan_range(tst[tl], tst[tl + 1]); }
    if (anyR) { ++tr; scan_range(tst[tr], tst[tr + 1]); }
  }

  float d = sqrtf(fmaxf(best + Q.w, 0.0f));
  for (int off = 32; off > 0; off >>= 1) d += __shfl_down(d, off, 64);
  if (lane == 0) atomicAdd(out, d);
}

extern "C" void kernel_launch(void* const* d_in, const int* in_sizes, int n_in,
                              void* d_out, int out_size, void* d_ws, size_t ws_size,
                              hipStream_t stream) {
  const float* p1 = (const float*)d_in[0];
  const float* p2 = (const float*)d_in[1];
  float* out = (float*)d_out;

  // ws layout (~772 KB): scat | cnt_blk | offs_blk | bstart
  float4* scat  = (float4*)d_ws;             // 2*NPTS float4 (512 KB)
  int* cnt_blk  = (int*)(scat + 2 * NPTS);   // CB*B (128 KB)
  int* offs_blk = cnt_blk + CB * B;          // CB*B (128 KB)
  int* bstart   = offs_blk + CB * B;         // 2*(B+1)

  chamfer_bin    <<<CB, 512, 0, stream>>>(p1, p2, cnt_blk);
  chamfer_scan   <<<1, B, 0, stream>>>(cnt_blk, offs_blk, bstart, out);
  chamfer_scatter<<<CB, 512, 0, stream>>>(p1, p2, offs_blk, scat);
  chamfer_search <<<512, 64, 0, stream>>>(scat, bstart, out);
}